// Round 3
// baseline (420.594 us; speedup 1.0000x reference)
//
#include <hip/hip_runtime.h>

// ---------------------------------------------------------------- constants
#define TTOK 32768
#define DM   256
#define NF   1024
#define KMAX 32

typedef __attribute__((ext_vector_type(8))) unsigned short ushort8;
typedef __attribute__((ext_vector_type(8))) __bf16 bf16x8;
typedef __attribute__((ext_vector_type(4))) float floatx4;

// workspace offsets (all 256B aligned)
constexpr size_t O_SLOT = 0;                                   // 1 uint (max|Wt|)
constexpr size_t O_S    = 256;                                 // 1024 f32 sigmoid(alpha)
constexpr size_t O_WCT  = O_S    + 4096;                       // Wc^T  [1024][256] bf16
constexpr size_t O_WGT  = O_WCT  + (size_t)NF*DM*2;            // Wg^T  [1024][256] bf16
constexpr size_t O_WDT  = O_WGT  + (size_t)NF*DM*2;            // Wd^T  [256][1024] bf16
constexpr size_t O_WTT  = O_WDT  + (size_t)DM*NF*2;            // Wt^T  [256][1024] f32
constexpr size_t O_XBF  = O_WTT  + (size_t)DM*NF*4;            // x bf16 [T][256]
constexpr size_t O_CNT  = O_XBF  + (size_t)TTOK*DM*2;          // counts [T]
constexpr size_t O_CIDX = O_CNT  + (size_t)TTOK*4;             // cand off(d*NF) [T][KMAX]
constexpr size_t O_CVAL = O_CIDX + (size_t)TTOK*KMAX*4;        // cand val [T][KMAX]
constexpr size_t O_TROP = O_CVAL + (size_t)TTOK*KMAX*4;        // trop bf16 [T][1024]
constexpr size_t O_FUSD = O_TROP + (size_t)TTOK*NF*2;          // fused bf16 [T][1024]

__device__ __forceinline__ float bf2f(unsigned short u) {
    union { unsigned int i; float f; } c; c.i = ((unsigned int)u) << 16; return c.f;
}
__device__ __forceinline__ unsigned short f2bf(float v) {
    union { float f; unsigned int i; } c; c.f = v;
    unsigned int b = c.i;
    return (unsigned short)((b + 0x7FFFu + ((b >> 16) & 1u)) >> 16);
}
__device__ __forceinline__ float sigm(float z) { return 1.0f / (1.0f + __expf(-z)); }
// tanh-gelu: max |diff| vs exact erf-gelu ~3e-3, far under 0.266 tolerance
__device__ __forceinline__ float gelu_f(float x) {
    return x * sigm(1.59576912f * (x + 0.044715f * x * x * x));
}
// async global->LDS, 16B per lane; lds dest = wave-uniform base + lane*16 [m97/m104]
__device__ __forceinline__ void g2lds16(const unsigned short* g, unsigned short* l) {
    __builtin_amdgcn_global_load_lds((const __attribute__((address_space(1))) unsigned int*)g,
                                     (__attribute__((address_space(3))) unsigned int*)l, 16, 0, 0);
}

// ------------------------------------------------- kernel 1: pack weights
__global__ void pack_kernel(const float* __restrict__ Wt, const float* __restrict__ alpha,
                            const float* __restrict__ Wc, const float* __restrict__ Wg,
                            const float* __restrict__ Wd,
                            unsigned short* __restrict__ Wct, unsigned short* __restrict__ Wgt,
                            unsigned short* __restrict__ WdT, float* __restrict__ WtT,
                            float* __restrict__ s, unsigned int* __restrict__ slot) {
    int e = blockIdx.x * 256 + threadIdx.x;
    if (e == 0) *slot = 0u;
    { int f = e >> 8, k = e & 255;           // Wc/Wg are [256][1024]
      Wct[e] = f2bf(Wc[k * NF + f]);
      Wgt[e] = f2bf(Wg[k * NF + f]); }
    { int n = e >> 10, k = e & 1023;         // Wd is [1024][256]
      WdT[e] = f2bf(Wd[k * DM + n]); }
    { int d = e >> 10, f = e & 1023;         // Wt is [1024][256]
      WtT[e] = Wt[f * DM + d]; }
    if (e < NF) s[e] = sigm(alpha[e]);
}

// ------------------------------------------------- kernel 2: max|Wt| reduce
__global__ void minmax_kernel(const float* __restrict__ Wt, unsigned int* __restrict__ slot) {
    int g = blockIdx.x * 256 + threadIdx.x;
    float lm = 0.0f;
    for (int i = g; i < NF * DM; i += 128 * 256) lm = fmaxf(lm, fabsf(Wt[i]));
    #pragma unroll
    for (int o = 32; o > 0; o >>= 1) lm = fmaxf(lm, __shfl_xor(lm, o));
    if ((threadIdx.x & 63) == 0) atomicMax(slot, __float_as_uint(lm)); // |w|>=0: uint order ok
}

// ------------------------------------------------- kernel 3: candidates + x->bf16
__global__ void cand_kernel(const float* __restrict__ x, const unsigned int* __restrict__ slot,
                            unsigned short* __restrict__ xbf, int* __restrict__ counts,
                            int* __restrict__ cidx, float* __restrict__ cval) {
    int i = blockIdx.x, t = threadIdx.x;
    float v = x[i * DM + t];
    xbf[i * DM + t] = f2bf(v);
    float m = v;
    #pragma unroll
    for (int o = 32; o > 0; o >>= 1) m = fmaxf(m, __shfl_xor(m, o));
    __shared__ float wm[4];
    __shared__ int cnt;
    __shared__ int sidx[KMAX];
    __shared__ float sval[KMAX];
    if ((t & 63) == 0) wm[t >> 6] = m;
    if (t == 0) cnt = 0;
    __syncthreads();
    float xmax = fmaxf(fmaxf(wm[0], wm[1]), fmaxf(wm[2], wm[3]));
    float delta = 2.0f * __uint_as_float(*slot);   // >= Wmax - Wmin : exact exclusion bound
    float thr = xmax - delta;
    if (v >= thr) {
        int p = atomicAdd(&cnt, 1);
        if (p < KMAX) { sidx[p] = t * NF; sval[p] = v; }   // premultiplied row offset
    }
    __syncthreads();
    int c = cnt;
    if (t == 0) counts[i] = c;
    if (t < (c < KMAX ? c : KMAX)) {
        cidx[i * KMAX + t] = sidx[t];
        cval[i * KMAX + t] = sval[t];
    }
}

// ------------------------------------------------- kernel 4: tropical part
// 256 thr, 32 tokens x 1024 features per block. Two-phase gather per k-round:
// issue all (<=32) independent WtT row loads, THEN consume -> vmcnt overlap
// instead of round-2's per-candidate load->fmax serialization (~200cyc each).
__global__ __launch_bounds__(256, 3) void trop_kernel(
    const float* __restrict__ x, const float* __restrict__ bt,
    const float* __restrict__ slx, const float* __restrict__ ofx,
    const float* __restrict__ slc, const float* __restrict__ ofc,
    const float* __restrict__ s, const float* __restrict__ WtT,
    const int* __restrict__ counts, const int* __restrict__ cidx,
    const float* __restrict__ cval, unsigned short* __restrict__ trop) {
    __shared__ int   sOff[32][KMAX];
    __shared__ float sVal[32][KMAX];
    __shared__ int   sKsh[32];
    int t = threadIdx.x, tok0 = blockIdx.x * 32;
    if (t < 32) sKsh[t] = counts[tok0 + t];
    for (int e = t; e < 32 * KMAX; e += 256) {
        int tk = e >> 5, k = e & 31;
        sOff[tk][k] = cidx[(tok0 + tk) * KMAX + k];
        sVal[tk][k] = cval[(tok0 + tk) * KMAX + k];
    }
    __syncthreads();
    int cK[32];
    unsigned int ovf = 0;
    int kmx = 0;
    #pragma unroll
    for (int tk = 0; tk < 32; tk++) {
        int c = sKsh[tk];
        if (c > KMAX) { ovf |= 1u << tk; c = 0; }   // overflow: full-scan later
        cK[tk] = c;
        kmx = c > kmx ? c : kmx;
    }
    for (int j = 0; j < 4; j++) {
        int f = j * 256 + t;
        float4 a0 = *(const float4*)(slx + f * 8), a1 = *(const float4*)(slx + f * 8 + 4);
        float4 b0 = *(const float4*)(ofx + f * 8), b1 = *(const float4*)(ofx + f * 8 + 4);
        float4 c0 = *(const float4*)(slc + f * 8), c1 = *(const float4*)(slc + f * 8 + 4);
        float4 d0 = *(const float4*)(ofc + f * 8), d1 = *(const float4*)(ofc + f * 8 + 4);
        float btf = bt[f], sf = s[f];
        float tm[32];
        #pragma unroll
        for (int tk = 0; tk < 32; tk++) tm[tk] = -1e30f;
        for (int k = 0; k < kmx; k++) {
            float lv[32];
            #pragma unroll
            for (int tk = 0; tk < 32; tk++)      // phase 1: issue loads (uniform branches)
                if (k < cK[tk]) lv[tk] = WtT[sOff[tk][k] + f];
            #pragma unroll
            for (int tk = 0; tk < 32; tk++)      // phase 2: consume
                if (k < cK[tk]) tm[tk] = fmaxf(tm[tk], sVal[tk][k] + lv[tk]);
        }
        if (ovf) {  // exact fallback, never expected
            #pragma unroll 1
            for (int tk = 0; tk < 32; tk++) if (ovf & (1u << tk)) {
                const float* xr = x + (tok0 + tk) * DM;
                float m2 = -1e30f;
                for (int d = 0; d < DM; d++) m2 = fmaxf(m2, xr[d] + WtT[d * NF + f]);
                tm[tk] = m2;
            }
        }
        #pragma unroll 1
        for (int tk = 0; tk < 32; tk++) {
            float z = tm[tk] + btf;
            float cvx = fmaf(z, a0.x, b0.x);
            cvx = fmaxf(cvx, fmaf(z, a0.y, b0.y));
            cvx = fmaxf(cvx, fmaf(z, a0.z, b0.z));
            cvx = fmaxf(cvx, fmaf(z, a0.w, b0.w));
            cvx = fmaxf(cvx, fmaf(z, a1.x, b1.x));
            cvx = fmaxf(cvx, fmaf(z, a1.y, b1.y));
            cvx = fmaxf(cvx, fmaf(z, a1.z, b1.z));
            cvx = fmaxf(cvx, fmaf(z, a1.w, b1.w));
            float ccv = fmaf(z, c0.x, d0.x);
            ccv = fminf(ccv, fmaf(z, c0.y, d0.y));
            ccv = fminf(ccv, fmaf(z, c0.z, d0.z));
            ccv = fminf(ccv, fmaf(z, c0.w, d0.w));
            ccv = fminf(ccv, fmaf(z, c1.x, d1.x));
            ccv = fminf(ccv, fmaf(z, c1.y, d1.y));
            ccv = fminf(ccv, fmaf(z, c1.z, d1.z));
            ccv = fminf(ccv, fmaf(z, c1.w, d1.w));
            trop[(tok0 + tk) * NF + f] = f2bf(sf * cvx + (1.0f - sf) * ccv);
        }
    }
}

// ------------------------------------------------- kernel 5: GEMM1 (x@Wc, x@Wg fused)
// 128x128 tile, BK=32, 512 thr (8 waves 2Mx4F, wave 64x32 dual-output).
// Staging via global_load_lds width=16: no VGPR round-trip (kills the staging
// temps that pushed round-2 past the 128-reg cap). LDS rows UNPADDED 64B
// (wave-uniform-base DMA requires lane-contiguous dest, m104/m108).
#define LDSS 32  // ushorts per row, no pad
__global__ __launch_bounds__(512, 4) void gemm1_kernel(
    const unsigned short* __restrict__ A,   // xbf [T][256]
    const unsigned short* __restrict__ Bct, // [1024][256]
    const unsigned short* __restrict__ Bgt, // [1024][256]
    const float* __restrict__ bc, const float* __restrict__ bg,
    const unsigned short* __restrict__ trop, unsigned short* __restrict__ fused) {
    __shared__ __align__(16) unsigned short As[128 * LDSS];
    __shared__ __align__(16) unsigned short Bcs[128 * LDSS];
    __shared__ __align__(16) unsigned short Bgs[128 * LDSS];
    const int t = threadIdx.x;
    const int bm = blockIdx.x, bf = blockIdx.y;
    const int wave = t >> 6, lane = t & 63;
    const int wm = wave & 1, wn = wave >> 1;
    const int lr = lane & 15, quad = lane >> 4;
    // DMA source row/col for this lane; wave w covers rows 16w..16w+15
    const int srow = wave * 16 + (lane >> 2), scol = (lane & 3) << 3;
    const unsigned short* gA = A   + (size_t)(bm * 128 + srow) * DM + scol;
    const unsigned short* gC = Bct + (size_t)(bf * 128 + srow) * DM + scol;
    const unsigned short* gG = Bgt + (size_t)(bf * 128 + srow) * DM + scol;
    unsigned short* lA = &As[wave * 16 * LDSS];
    unsigned short* lC = &Bcs[wave * 16 * LDSS];
    unsigned short* lG = &Bgs[wave * 16 * LDSS];

    floatx4 accc[4][2], accg[4][2];
    #pragma unroll
    for (int i = 0; i < 4; i++)
        #pragma unroll
        for (int j = 0; j < 2; j++) { accc[i][j] = (floatx4)0.0f; accg[i][j] = (floatx4)0.0f; }

    for (int k0 = 0; k0 < DM; k0 += 32) {
        __syncthreads();                    // prior tile's ds_reads done
        g2lds16(gA + k0, lA);
        g2lds16(gC + k0, lC);
        g2lds16(gG + k0, lG);
        __syncthreads();                    // vmcnt drained before barrier
        bf16x8 af[4], bcf[2], bgf[2];
        #pragma unroll
        for (int mi = 0; mi < 4; mi++)
            af[mi] = *(const bf16x8*)&As[(wm * 64 + mi * 16 + lr) * LDSS + quad * 8];
        #pragma unroll
        for (int ni = 0; ni < 2; ni++) {
            bcf[ni] = *(const bf16x8*)&Bcs[(wn * 32 + ni * 16 + lr) * LDSS + quad * 8];
            bgf[ni] = *(const bf16x8*)&Bgs[(wn * 32 + ni * 16 + lr) * LDSS + quad * 8];
        }
        #pragma unroll
        for (int mi = 0; mi < 4; mi++)
            #pragma unroll
            for (int ni = 0; ni < 2; ni++) {
                accc[mi][ni] = __builtin_amdgcn_mfma_f32_16x16x32_bf16(af[mi], bcf[ni], accc[mi][ni], 0, 0, 0);
                accg[mi][ni] = __builtin_amdgcn_mfma_f32_16x16x32_bf16(af[mi], bgf[ni], accg[mi][ni], 0, 0, 0);
            }
    }
    // epilogue: C/D layout col=lane&15, row=quad*4+r  [verified m89/m91]
    #pragma unroll
    for (int mi = 0; mi < 4; mi++)
        #pragma unroll
        for (int ni = 0; ni < 2; ni++) {
            int f = bf * 128 + wn * 32 + ni * 16 + lr;
            float bcv = bc[f], bgv = bg[f];
            #pragma unroll
            for (int r = 0; r < 4; r++) {
                int m = bm * 128 + wm * 64 + mi * 16 + quad * 4 + r;
                float cpre = accc[mi][ni][r] + bcv;
                float gpre = accg[mi][ni][r] + bgv;
                float g = sigm(gpre);
                float cla = gelu_f(cpre);
                float tr = bf2f(trop[m * NF + f]);
                fused[m * NF + f] = f2bf(g * tr + (1.0f - g) * cla);
            }
        }
}

// ------------------------------------------------- kernel 6: GEMM2 (fused@Wd + bd)
__global__ __launch_bounds__(512, 4) void gemm2_kernel(
    const unsigned short* __restrict__ A,  // fused [T][1024]
    const unsigned short* __restrict__ Bt, // WdT [256][1024]
    const float* __restrict__ bd, float* __restrict__ out) {
    __shared__ __align__(16) unsigned short As[128 * LDSS];
    __shared__ __align__(16) unsigned short Bs[128 * LDSS];
    const int t = threadIdx.x;
    const int bm = blockIdx.x, bn = blockIdx.y;
    const int wave = t >> 6, lane = t & 63;
    const int wm = wave & 1, wn = wave >> 1;
    const int lr = lane & 15, quad = lane >> 4;
    const int srow = wave * 16 + (lane >> 2), scol = (lane & 3) << 3;
    const unsigned short* gA = A  + (size_t)(bm * 128 + srow) * NF + scol;
    const unsigned short* gB = Bt + (size_t)(bn * 128 + srow) * NF + scol;
    unsigned short* lA = &As[wave * 16 * LDSS];
    unsigned short* lB = &Bs[wave * 16 * LDSS];

    floatx4 acc[4][2];
    #pragma unroll
    for (int i = 0; i < 4; i++)
        #pragma unroll
        for (int j = 0; j < 2; j++) acc[i][j] = (floatx4)0.0f;

    for (int k0 = 0; k0 < NF; k0 += 32) {
        __syncthreads();
        g2lds16(gA + k0, lA);
        g2lds16(gB + k0, lB);
        __syncthreads();
        bf16x8 af[4], bf_[2];
        #pragma unroll
        for (int mi = 0; mi < 4; mi++)
            af[mi] = *(const bf16x8*)&As[(wm * 64 + mi * 16 + lr) * LDSS + quad * 8];
        #pragma unroll
        for (int ni = 0; ni < 2; ni++)
            bf_[ni] = *(const bf16x8*)&Bs[(wn * 32 + ni * 16 + lr) * LDSS + quad * 8];
        #pragma unroll
        for (int mi = 0; mi < 4; mi++)
            #pragma unroll
            for (int ni = 0; ni < 2; ni++)
                acc[mi][ni] = __builtin_amdgcn_mfma_f32_16x16x32_bf16(af[mi], bf_[ni], acc[mi][ni], 0, 0, 0);
    }
    #pragma unroll
    for (int mi = 0; mi < 4; mi++)
        #pragma unroll
        for (int ni = 0; ni < 2; ni++) {
            int n = bn * 128 + wn * 32 + ni * 16 + lr;
            float bdv = bd[n];
            #pragma unroll
            for (int r = 0; r < 4; r++) {
                int m = bm * 128 + wm * 64 + mi * 16 + quad * 4 + r;
                out[m * DM + n] = acc[mi][ni][r] + bdv;
            }
        }
}

// ------------------------------------------------------------- launcher
extern "C" void kernel_launch(void* const* d_in, const int* in_sizes, int n_in,
                              void* d_out, int out_size, void* d_ws, size_t ws_size,
                              hipStream_t stream) {
    const float* x     = (const float*)d_in[0];
    const float* Wt    = (const float*)d_in[1];
    const float* bt    = (const float*)d_in[2];
    const float* slx   = (const float*)d_in[3];
    const float* ofx   = (const float*)d_in[4];
    const float* slc   = (const float*)d_in[5];
    const float* ofc   = (const float*)d_in[6];
    const float* alpha = (const float*)d_in[7];
    const float* Wc    = (const float*)d_in[8];
    const float* bc    = (const float*)d_in[9];
    const float* Wg    = (const float*)d_in[10];
    const float* bg    = (const float*)d_in[11];
    const float* Wd    = (const float*)d_in[12];
    const float* bd    = (const float*)d_in[13];
    float* out = (float*)d_out;
    char* ws = (char*)d_ws;

    unsigned int* slot = (unsigned int*)(ws + O_SLOT);
    float* s           = (float*)(ws + O_S);
    unsigned short* Wct = (unsigned short*)(ws + O_WCT);
    unsigned short* Wgt = (unsigned short*)(ws + O_WGT);
    unsigned short* WdT = (unsigned short*)(ws + O_WDT);
    float* WtT          = (float*)(ws + O_WTT);
    unsigned short* xbf = (unsigned short*)(ws + O_XBF);
    int* counts         = (int*)(ws + O_CNT);
    int* cidx           = (int*)(ws + O_CIDX);
    float* cval         = (float*)(ws + O_CVAL);
    unsigned short* trop  = (unsigned short*)(ws + O_TROP);
    unsigned short* fused = (unsigned short*)(ws + O_FUSD);

    pack_kernel<<<1024, 256, 0, stream>>>(Wt, alpha, Wc, Wg, Wd, Wct, Wgt, WdT, WtT, s, slot);
    minmax_kernel<<<128, 256, 0, stream>>>(Wt, slot);
    cand_kernel<<<TTOK, 256, 0, stream>>>(x, slot, xbf, counts, cidx, cval);
    trop_kernel<<<TTOK / 32, 256, 0, stream>>>(x, bt, slx, ofx, slc, ofc, s, WtT,
                                               counts, cidx, cval, trop);
    gemm1_kernel<<<dim3(TTOK / 128, NF / 128), 512, 0, stream>>>(xbf, Wct, Wgt, bc, bg, trop, fused);
    gemm2_kernel<<<dim3(TTOK / 128, DM / 128), 512, 0, stream>>>(fused, WdT, bd, out);
}

// Round 4
// 326.287 us; speedup vs baseline: 1.2890x; 1.2890x over previous
//
#include <hip/hip_runtime.h>

// ---------------------------------------------------------------- constants
#define TTOK 32768
#define DM   256
#define NF   1024
#define KMAX 32

typedef __attribute__((ext_vector_type(8))) unsigned short ushort8;
typedef __attribute__((ext_vector_type(8))) __bf16 bf16x8;
typedef __attribute__((ext_vector_type(4))) float floatx4;

// workspace offsets (all 256B aligned)
constexpr size_t O_SLOT = 0;                                   // 1 uint (max|Wt|)
constexpr size_t O_S    = 256;                                 // 1024 f32 sigmoid(alpha)
constexpr size_t O_WCT  = O_S    + 4096;                       // Wc^T  [1024][256] bf16
constexpr size_t O_WGT  = O_WCT  + (size_t)NF*DM*2;            // Wg^T  [1024][256] bf16
constexpr size_t O_WDT  = O_WGT  + (size_t)NF*DM*2;            // Wd^T  [256][1024] bf16
constexpr size_t O_WTT  = O_WDT  + (size_t)DM*NF*2;            // Wt^T  [256][1024] f32
constexpr size_t O_XBF  = O_WTT  + (size_t)DM*NF*4;            // x bf16 [T][256]
constexpr size_t O_CNT  = O_XBF  + (size_t)TTOK*DM*2;          // counts [T]
constexpr size_t O_CIDX = O_CNT  + (size_t)TTOK*4;             // cand off(d*NF) [T][KMAX]
constexpr size_t O_CVAL = O_CIDX + (size_t)TTOK*KMAX*4;        // cand val [T][KMAX]
constexpr size_t O_TROP = O_CVAL + (size_t)TTOK*KMAX*4;        // trop bf16 [T][1024]
constexpr size_t O_FUSD = O_TROP + (size_t)TTOK*NF*2;          // fused bf16 [T][1024]

__device__ __forceinline__ float bf2f(unsigned short u) {
    union { unsigned int i; float f; } c; c.i = ((unsigned int)u) << 16; return c.f;
}
__device__ __forceinline__ unsigned short f2bf(float v) {
    union { float f; unsigned int i; } c; c.f = v;
    unsigned int b = c.i;
    return (unsigned short)((b + 0x7FFFu + ((b >> 16) & 1u)) >> 16);
}
__device__ __forceinline__ float sigm(float z) { return 1.0f / (1.0f + __expf(-z)); }
// tanh-gelu: max |diff| vs exact erf-gelu ~3e-3, far under 0.266 tolerance
__device__ __forceinline__ float gelu_f(float x) {
    return x * sigm(1.59576912f * (x + 0.044715f * x * x * x));
}
// async global->LDS, 16B per lane; lds dest = wave-uniform base + lane*16 [m97/m104]
__device__ __forceinline__ void g2lds16(const unsigned short* g, unsigned short* l) {
    __builtin_amdgcn_global_load_lds((const __attribute__((address_space(1))) unsigned int*)g,
                                     (__attribute__((address_space(3))) unsigned int*)l, 16, 0, 0);
}
__device__ __forceinline__ float4 f4maxadd(float4 acc, float v, float4 r) {
    acc.x = fmaxf(acc.x, v + r.x); acc.y = fmaxf(acc.y, v + r.y);
    acc.z = fmaxf(acc.z, v + r.z); acc.w = fmaxf(acc.w, v + r.w);
    return acc;
}

// ------------------------------------------------- kernel 1: pack weights
__global__ void pack_kernel(const float* __restrict__ Wt, const float* __restrict__ alpha,
                            const float* __restrict__ Wc, const float* __restrict__ Wg,
                            const float* __restrict__ Wd,
                            unsigned short* __restrict__ Wct, unsigned short* __restrict__ Wgt,
                            unsigned short* __restrict__ WdT, float* __restrict__ WtT,
                            float* __restrict__ s, unsigned int* __restrict__ slot) {
    int e = blockIdx.x * 256 + threadIdx.x;
    if (e == 0) *slot = 0u;
    { int f = e >> 8, k = e & 255;           // Wc/Wg are [256][1024]
      Wct[e] = f2bf(Wc[k * NF + f]);
      Wgt[e] = f2bf(Wg[k * NF + f]); }
    { int n = e >> 10, k = e & 1023;         // Wd is [1024][256]
      WdT[e] = f2bf(Wd[k * DM + n]); }
    { int d = e >> 10, f = e & 1023;         // Wt is [1024][256]
      WtT[e] = Wt[f * DM + d]; }
    if (e < NF) s[e] = sigm(alpha[e]);
}

// ------------------------------------------------- kernel 2: max|Wt| reduce
__global__ void minmax_kernel(const float* __restrict__ Wt, unsigned int* __restrict__ slot) {
    int g = blockIdx.x * 256 + threadIdx.x;
    float lm = 0.0f;
    for (int i = g; i < NF * DM; i += 128 * 256) lm = fmaxf(lm, fabsf(Wt[i]));
    #pragma unroll
    for (int o = 32; o > 0; o >>= 1) lm = fmaxf(lm, __shfl_xor(lm, o));
    if ((threadIdx.x & 63) == 0) atomicMax(slot, __float_as_uint(lm)); // |w|>=0: uint order ok
}

// ------------------------------------------------- kernel 3: candidates + x->bf16
__global__ void cand_kernel(const float* __restrict__ x, const unsigned int* __restrict__ slot,
                            unsigned short* __restrict__ xbf, int* __restrict__ counts,
                            int* __restrict__ cidx, float* __restrict__ cval) {
    int i = blockIdx.x, t = threadIdx.x;
    float v = x[i * DM + t];
    xbf[i * DM + t] = f2bf(v);
    float m = v;
    #pragma unroll
    for (int o = 32; o > 0; o >>= 1) m = fmaxf(m, __shfl_xor(m, o));
    __shared__ float wm[4];
    __shared__ int cnt;
    __shared__ int sidx[KMAX];
    __shared__ float sval[KMAX];
    if ((t & 63) == 0) wm[t >> 6] = m;
    if (t == 0) cnt = 0;
    __syncthreads();
    float xmax = fmaxf(fmaxf(wm[0], wm[1]), fmaxf(wm[2], wm[3]));
    float delta = 2.0f * __uint_as_float(*slot);   // >= Wmax - Wmin : exact exclusion bound
    float thr = xmax - delta;
    if (v >= thr) {
        int p = atomicAdd(&cnt, 1);
        if (p < KMAX) { sidx[p] = t * NF; sval[p] = v; }   // premultiplied row offset
    }
    __syncthreads();
    int c = cnt;
    if (t == 0) counts[i] = c;
    if (t < (c < KMAX ? c : KMAX)) {
        cidx[i * KMAX + t] = sidx[t];
        cval[i * KMAX + t] = sval[t];
    }
}

// ------------------------------------------------- kernel 4: tropical part
// Block = 16 tokens x 1024 features, 256 thr, grid 2048.
//  A: stage candidate meta PRE-PADDED (off=0,val=-1e30) -> branchless hot loop.
//  B: per token-PAIR, k-unroll x2 -> 4 independent coalesced float4 row loads
//     in flight; tm as float4/token; dump to z[ff][tk][t] (bf16, LDS 32KB).
//     (round-3 lesson: 32-deep arrays spill; LDS is the spill target, not scratch)
//  C: ff-outer: 32-reg param block loaded once per ff, amortized over 16 tokens;
//     z read back stride-1 conflict-free; 30-op epilogue; store.
__global__ __launch_bounds__(256, 4) void trop_kernel(
    const float* __restrict__ x, const float* __restrict__ bt,
    const float* __restrict__ slx, const float* __restrict__ ofx,
    const float* __restrict__ slc, const float* __restrict__ ofc,
    const float* __restrict__ s, const float* __restrict__ WtT,
    const int* __restrict__ counts, const int* __restrict__ cidx,
    const float* __restrict__ cval, unsigned short* __restrict__ trop) {
    __shared__ int   sCnt[16];
    __shared__ int   sOff[16][KMAX];
    __shared__ float sVal[16][KMAX];
    __shared__ unsigned short zs[64 * 256];   // [ff*16+tk][t] 32KB
    const int t = threadIdx.x, tok0 = blockIdx.x * 16, t4 = t * 4;

    if (t < 16) sCnt[t] = counts[tok0 + t];
    #pragma unroll
    for (int e = t; e < 16 * KMAX; e += 256) { ((int*)sOff)[e] = 0; ((float*)sVal)[e] = -1e30f; }
    __syncthreads();
    #pragma unroll
    for (int e = t; e < 16 * KMAX; e += 256) {
        int tk = e >> 5, k = e & 31;
        int c = sCnt[tk];
        if (k < (c < KMAX ? c : KMAX)) {
            ((int*)sOff)[e]   = cidx[(tok0 + tk) * KMAX + k];
            ((float*)sVal)[e] = cval[(tok0 + tk) * KMAX + k];
        }
    }
    __syncthreads();

    // ---- phase B: max-plus
    for (int tp = 0; tp < 16; tp += 2) {
        int ca = sCnt[tp],     cb = sCnt[tp + 1];
        int Ka = ca > KMAX ? 0 : ((ca + 1) & ~1);    // padded-even; overflow -> 0 (fallback below)
        int Kb = cb > KMAX ? 0 : ((cb + 1) & ~1);
        int km = Ka > Kb ? Ka : Kb;                  // uniform across block
        float4 tmA = make_float4(-1e30f, -1e30f, -1e30f, -1e30f);
        float4 tmB = tmA;
        for (int k = 0; k < km; k += 2) {
            int   oA0 = sOff[tp][k],     oA1 = sOff[tp][k + 1];
            int   oB0 = sOff[tp + 1][k], oB1 = sOff[tp + 1][k + 1];
            float vA0 = sVal[tp][k],     vA1 = sVal[tp][k + 1];
            float vB0 = sVal[tp + 1][k], vB1 = sVal[tp + 1][k + 1];
            float4 rA0 = *(const float4*)(WtT + oA0 + t4);
            float4 rA1 = *(const float4*)(WtT + oA1 + t4);
            float4 rB0 = *(const float4*)(WtT + oB0 + t4);
            float4 rB1 = *(const float4*)(WtT + oB1 + t4);
            tmA = f4maxadd(tmA, vA0, rA0);
            tmA = f4maxadd(tmA, vA1, rA1);
            tmB = f4maxadd(tmB, vB0, rB0);
            tmB = f4maxadd(tmB, vB1, rB1);
        }
        // exact fallback for overflowed tokens (never expected)
        if (ca > KMAX) {
            tmA = make_float4(-1e30f, -1e30f, -1e30f, -1e30f);
            for (int d = 0; d < DM; d++) {
                float xv = x[(size_t)(tok0 + tp) * DM + d];
                tmA = f4maxadd(tmA, xv, *(const float4*)(WtT + d * NF + t4));
            }
        }
        if (cb > KMAX) {
            tmB = make_float4(-1e30f, -1e30f, -1e30f, -1e30f);
            for (int d = 0; d < DM; d++) {
                float xv = x[(size_t)(tok0 + tp + 1) * DM + d];
                tmB = f4maxadd(tmB, xv, *(const float4*)(WtT + d * NF + t4));
            }
        }
        zs[(0 * 16 + tp) * 256 + t] = f2bf(tmA.x);
        zs[(1 * 16 + tp) * 256 + t] = f2bf(tmA.y);
        zs[(2 * 16 + tp) * 256 + t] = f2bf(tmA.z);
        zs[(3 * 16 + tp) * 256 + t] = f2bf(tmA.w);
        zs[(0 * 16 + tp + 1) * 256 + t] = f2bf(tmB.x);
        zs[(1 * 16 + tp + 1) * 256 + t] = f2bf(tmB.y);
        zs[(2 * 16 + tp + 1) * 256 + t] = f2bf(tmB.z);
        zs[(3 * 16 + tp + 1) * 256 + t] = f2bf(tmB.w);
    }
    __syncthreads();   // not strictly needed (same-thread readback) but cheap

    // ---- phase C: convex/concave epilogue, ff-outer to amortize param regs
    for (int ff = 0; ff < 4; ff++) {
        int f = t4 + ff;
        float4 a0 = *(const float4*)(slx + f * 8), a1 = *(const float4*)(slx + f * 8 + 4);
        float4 b0 = *(const float4*)(ofx + f * 8), b1 = *(const float4*)(ofx + f * 8 + 4);
        float4 c0 = *(const float4*)(slc + f * 8), c1 = *(const float4*)(slc + f * 8 + 4);
        float4 d0 = *(const float4*)(ofc + f * 8), d1 = *(const float4*)(ofc + f * 8 + 4);
        float btf = bt[f], sf = s[f];
        #pragma unroll 4
        for (int tk = 0; tk < 16; tk++) {
            float z = bf2f(zs[(ff * 16 + tk) * 256 + t]) + btf;
            float cvx = fmaf(z, a0.x, b0.x);
            cvx = fmaxf(cvx, fmaf(z, a0.y, b0.y));
            cvx = fmaxf(cvx, fmaf(z, a0.z, b0.z));
            cvx = fmaxf(cvx, fmaf(z, a0.w, b0.w));
            cvx = fmaxf(cvx, fmaf(z, a1.x, b1.x));
            cvx = fmaxf(cvx, fmaf(z, a1.y, b1.y));
            cvx = fmaxf(cvx, fmaf(z, a1.z, b1.z));
            cvx = fmaxf(cvx, fmaf(z, a1.w, b1.w));
            float ccv = fmaf(z, c0.x, d0.x);
            ccv = fminf(ccv, fmaf(z, c0.y, d0.y));
            ccv = fminf(ccv, fmaf(z, c0.z, d0.z));
            ccv = fminf(ccv, fmaf(z, c0.w, d0.w));
            ccv = fminf(ccv, fmaf(z, c1.x, d1.x));
            ccv = fminf(ccv, fmaf(z, c1.y, d1.y));
            ccv = fminf(ccv, fmaf(z, c1.z, d1.z));
            ccv = fminf(ccv, fmaf(z, c1.w, d1.w));
            trop[(size_t)(tok0 + tk) * NF + f] = f2bf(sf * cvx + (1.0f - sf) * ccv);
        }
    }
}

// ------------------------------------------------- kernel 5: GEMM1 (x@Wc, x@Wg fused)
// 128x128 tile, BK=32, 512 thr (8 waves 2Mx4F, wave 64x32 dual-output).
// Staging via global_load_lds width=16; LDS rows UNPADDED 64B (m104/m108).
#define LDSS 32  // ushorts per row, no pad
__global__ __launch_bounds__(512, 4) void gemm1_kernel(
    const unsigned short* __restrict__ A,   // xbf [T][256]
    const unsigned short* __restrict__ Bct, // [1024][256]
    const unsigned short* __restrict__ Bgt, // [1024][256]
    const float* __restrict__ bc, const float* __restrict__ bg,
    const unsigned short* __restrict__ trop, unsigned short* __restrict__ fused) {
    __shared__ __align__(16) unsigned short As[128 * LDSS];
    __shared__ __align__(16) unsigned short Bcs[128 * LDSS];
    __shared__ __align__(16) unsigned short Bgs[128 * LDSS];
    const int t = threadIdx.x;
    const int bm = blockIdx.x, bf = blockIdx.y;
    const int wave = t >> 6, lane = t & 63;
    const int wm = wave & 1, wn = wave >> 1;
    const int lr = lane & 15, quad = lane >> 4;
    const int srow = wave * 16 + (lane >> 2), scol = (lane & 3) << 3;
    const unsigned short* gA = A   + (size_t)(bm * 128 + srow) * DM + scol;
    const unsigned short* gC = Bct + (size_t)(bf * 128 + srow) * DM + scol;
    const unsigned short* gG = Bgt + (size_t)(bf * 128 + srow) * DM + scol;
    unsigned short* lA = &As[wave * 16 * LDSS];
    unsigned short* lC = &Bcs[wave * 16 * LDSS];
    unsigned short* lG = &Bgs[wave * 16 * LDSS];

    floatx4 accc[4][2], accg[4][2];
    #pragma unroll
    for (int i = 0; i < 4; i++)
        #pragma unroll
        for (int j = 0; j < 2; j++) { accc[i][j] = (floatx4)0.0f; accg[i][j] = (floatx4)0.0f; }

    for (int k0 = 0; k0 < DM; k0 += 32) {
        __syncthreads();
        g2lds16(gA + k0, lA);
        g2lds16(gC + k0, lC);
        g2lds16(gG + k0, lG);
        __syncthreads();
        bf16x8 af[4], bcf[2], bgf[2];
        #pragma unroll
        for (int mi = 0; mi < 4; mi++)
            af[mi] = *(const bf16x8*)&As[(wm * 64 + mi * 16 + lr) * LDSS + quad * 8];
        #pragma unroll
        for (int ni = 0; ni < 2; ni++) {
            bcf[ni] = *(const bf16x8*)&Bcs[(wn * 32 + ni * 16 + lr) * LDSS + quad * 8];
            bgf[ni] = *(const bf16x8*)&Bgs[(wn * 32 + ni * 16 + lr) * LDSS + quad * 8];
        }
        #pragma unroll
        for (int mi = 0; mi < 4; mi++)
            #pragma unroll
            for (int ni = 0; ni < 2; ni++) {
                accc[mi][ni] = __builtin_amdgcn_mfma_f32_16x16x32_bf16(af[mi], bcf[ni], accc[mi][ni], 0, 0, 0);
                accg[mi][ni] = __builtin_amdgcn_mfma_f32_16x16x32_bf16(af[mi], bgf[ni], accg[mi][ni], 0, 0, 0);
            }
    }
    // epilogue: C/D layout col=lane&15, row=quad*4+r  [verified m89/m91]
    #pragma unroll
    for (int mi = 0; mi < 4; mi++)
        #pragma unroll
        for (int ni = 0; ni < 2; ni++) {
            int f = bf * 128 + wn * 32 + ni * 16 + lr;
            float bcv = bc[f], bgv = bg[f];
            #pragma unroll
            for (int r = 0; r < 4; r++) {
                int m = bm * 128 + wm * 64 + mi * 16 + quad * 4 + r;
                float cpre = accc[mi][ni][r] + bcv;
                float gpre = accg[mi][ni][r] + bgv;
                float g = sigm(gpre);
                float cla = gelu_f(cpre);
                float tr = bf2f(trop[m * NF + f]);
                fused[m * NF + f] = f2bf(g * tr + (1.0f - g) * cla);
            }
        }
}

// ------------------------------------------------- kernel 6: GEMM2 (fused@Wd + bd)
__global__ __launch_bounds__(512, 4) void gemm2_kernel(
    const unsigned short* __restrict__ A,  // fused [T][1024]
    const unsigned short* __restrict__ Bt, // WdT [256][1024]
    const float* __restrict__ bd, float* __restrict__ out) {
    __shared__ __align__(16) unsigned short As[128 * LDSS];
    __shared__ __align__(16) unsigned short Bs[128 * LDSS];
    const int t = threadIdx.x;
    const int bm = blockIdx.x, bn = blockIdx.y;
    const int wave = t >> 6, lane = t & 63;
    const int wm = wave & 1, wn = wave >> 1;
    const int lr = lane & 15, quad = lane >> 4;
    const int srow = wave * 16 + (lane >> 2), scol = (lane & 3) << 3;
    const unsigned short* gA = A  + (size_t)(bm * 128 + srow) * NF + scol;
    const unsigned short* gB = Bt + (size_t)(bn * 128 + srow) * NF + scol;
    unsigned short* lA = &As[wave * 16 * LDSS];
    unsigned short* lB = &Bs[wave * 16 * LDSS];

    floatx4 acc[4][2];
    #pragma unroll
    for (int i = 0; i < 4; i++)
        #pragma unroll
        for (int j = 0; j < 2; j++) acc[i][j] = (floatx4)0.0f;

    for (int k0 = 0; k0 < NF; k0 += 32) {
        __syncthreads();
        g2lds16(gA + k0, lA);
        g2lds16(gB + k0, lB);
        __syncthreads();
        bf16x8 af[4], bf_[2];
        #pragma unroll
        for (int mi = 0; mi < 4; mi++)
            af[mi] = *(const bf16x8*)&As[(wm * 64 + mi * 16 + lr) * LDSS + quad * 8];
        #pragma unroll
        for (int ni = 0; ni < 2; ni++)
            bf_[ni] = *(const bf16x8*)&Bs[(wn * 32 + ni * 16 + lr) * LDSS + quad * 8];
        #pragma unroll
        for (int mi = 0; mi < 4; mi++)
            #pragma unroll
            for (int ni = 0; ni < 2; ni++)
                acc[mi][ni] = __builtin_amdgcn_mfma_f32_16x16x32_bf16(af[mi], bf_[ni], acc[mi][ni], 0, 0, 0);
    }
    #pragma unroll
    for (int mi = 0; mi < 4; mi++)
        #pragma unroll
        for (int ni = 0; ni < 2; ni++) {
            int n = bn * 128 + wn * 32 + ni * 16 + lr;
            float bdv = bd[n];
            #pragma unroll
            for (int r = 0; r < 4; r++) {
                int m = bm * 128 + wm * 64 + mi * 16 + quad * 4 + r;
                out[m * DM + n] = acc[mi][ni][r] + bdv;
            }
        }
}

// ------------------------------------------------------------- launcher
extern "C" void kernel_launch(void* const* d_in, const int* in_sizes, int n_in,
                              void* d_out, int out_size, void* d_ws, size_t ws_size,
                              hipStream_t stream) {
    const float* x     = (const float*)d_in[0];
    const float* Wt    = (const float*)d_in[1];
    const float* bt    = (const float*)d_in[2];
    const float* slx   = (const float*)d_in[3];
    const float* ofx   = (const float*)d_in[4];
    const float* slc   = (const float*)d_in[5];
    const float* ofc   = (const float*)d_in[6];
    const float* alpha = (const float*)d_in[7];
    const float* Wc    = (const float*)d_in[8];
    const float* bc    = (const float*)d_in[9];
    const float* Wg    = (const float*)d_in[10];
    const float* bg    = (const float*)d_in[11];
    const float* Wd    = (const float*)d_in[12];
    const float* bd    = (const float*)d_in[13];
    float* out = (float*)d_out;
    char* ws = (char*)d_ws;

    unsigned int* slot = (unsigned int*)(ws + O_SLOT);
    float* s           = (float*)(ws + O_S);
    unsigned short* Wct = (unsigned short*)(ws + O_WCT);
    unsigned short* Wgt = (unsigned short*)(ws + O_WGT);
    unsigned short* WdT = (unsigned short*)(ws + O_WDT);
    float* WtT          = (float*)(ws + O_WTT);
    unsigned short* xbf = (unsigned short*)(ws + O_XBF);
    int* counts         = (int*)(ws + O_CNT);
    int* cidx           = (int*)(ws + O_CIDX);
    float* cval         = (float*)(ws + O_CVAL);
    unsigned short* trop  = (unsigned short*)(ws + O_TROP);
    unsigned short* fused = (unsigned short*)(ws + O_FUSD);

    pack_kernel<<<1024, 256, 0, stream>>>(Wt, alpha, Wc, Wg, Wd, Wct, Wgt, WdT, WtT, s, slot);
    minmax_kernel<<<128, 256, 0, stream>>>(Wt, slot);
    cand_kernel<<<TTOK, 256, 0, stream>>>(x, slot, xbf, counts, cidx, cval);
    trop_kernel<<<TTOK / 16, 256, 0, stream>>>(x, bt, slx, ofx, slc, ofc, s, WtT,
                                               counts, cidx, cval, trop);
    gemm1_kernel<<<dim3(TTOK / 128, NF / 128), 512, 0, stream>>>(xbf, Wct, Wgt, bc, bg, trop, fused);
    gemm2_kernel<<<dim3(TTOK / 128, DM / 128), 512, 0, stream>>>(fused, WdT, bd, out);
}